// Round 18
// baseline (459.944 us; speedup 1.0000x reference)
//
#include <hip/hip_runtime.h>
#include <hip/hip_cooperative_groups.h>
#include <hip/hip_fp16.h>
#include <math.h>

#define BLK 256
namespace cg = cooperative_groups;

typedef _Float16 half8 __attribute__((ext_vector_type(8)));
typedef float f32x4 __attribute__((ext_vector_type(4)));
typedef float f32x2 __attribute__((ext_vector_type(2)));

__device__ inline void fp8x8_add(uint2 r, float* __restrict__ acc) {
    f32x2 f01 = __builtin_amdgcn_cvt_pk_f32_fp8((int)r.x, false);
    f32x2 f23 = __builtin_amdgcn_cvt_pk_f32_fp8((int)r.x, true);
    f32x2 f45 = __builtin_amdgcn_cvt_pk_f32_fp8((int)r.y, false);
    f32x2 f67 = __builtin_amdgcn_cvt_pk_f32_fp8((int)r.y, true);
    acc[0] += f01[0]; acc[1] += f01[1];
    acc[2] += f23[0]; acc[3] += f23[1];
    acc[4] += f45[0]; acc[5] += f45[1];
    acc[6] += f67[0]; acc[7] += f67[1];
}

// ============ single cooperative mega-kernel: all 6 phases, 5 grid syncs ============
__global__ __launch_bounds__(256, 4) void mega_kernel(
    const int* __restrict__ dst, const int* __restrict__ srcp,
    int* __restrict__ countmat, int* __restrict__ total, int* __restrict__ bbase,
    unsigned* __restrict__ sorted, int* __restrict__ rowptr, float* __restrict__ dinv,
    int* __restrict__ csr_src, unsigned char* __restrict__ hs8, __half* __restrict__ hs2,
    __half* __restrict__ wt0, __half* __restrict__ wt1,
    const float* __restrict__ W0, const float* __restrict__ W1,
    const float* __restrict__ x, const float* __restrict__ b0,
    const float* __restrict__ b1, float* __restrict__ out,
    int N, int E, int nbkt, int CB) {
    cg::grid_group grid = cg::this_grid();
    __shared__ __align__(16) char smem[5632];
    const int tid = threadIdx.x;
    const int WG = (128 * 128 + 64 * 128 + BLK - 1) / BLK;

    // ---- Phase A: chunk histograms + weight convert ----
    {
        int* h = (int*)smem;
        for (int bb = blockIdx.x; bb < CB + WG; bb += gridDim.x) {
            if (bb < CB) {
                h[tid] = 0;
                __syncthreads();
                int e0 = bb * 1024;
                int lim = min(e0 + 1024, E);
                for (int e = e0 + tid; e < lim; e += 256) atomicAdd(&h[dst[e] >> 8], 1);
                __syncthreads();
                if (tid < nbkt) countmat[(size_t)bb * nbkt + tid] = h[tid];
            } else {
                int u = (bb - CB) * 256 + tid;
                if (u < 128 * 128) {
                    int c = u >> 7, k = u & 127;
                    wt0[u] = __float2half(W0[k * 128 + c]);
                } else if (u < 128 * 128 + 64 * 128) {
                    int v = u - 128 * 128;
                    int c = v >> 7, k = v & 127;
                    wt1[v] = __float2half(W1[k * 64 + c]);
                }
            }
            __syncthreads();
        }
    }
    grid.sync();

    // ---- Phase B: per-bucket exclusive scan over chunks ----
    {
        int* s = (int*)smem;
        for (int b = blockIdx.x; b < nbkt; b += gridDim.x) {
            int v[4];
            int sum = 0;
            #pragma unroll
            for (int j = 0; j < 4; ++j) {
                int i = tid * 4 + j;
                v[j] = (i < CB) ? countmat[(size_t)i * nbkt + b] : 0;
                sum += v[j];
            }
            s[tid] = sum;
            __syncthreads();
            #pragma unroll
            for (int off = 1; off < BLK; off <<= 1) {
                int t = 0;
                if (tid >= off) t = s[tid - off];
                __syncthreads();
                if (tid >= off) s[tid] += t;
                __syncthreads();
            }
            int run = s[tid] - sum;
            #pragma unroll
            for (int j = 0; j < 4; ++j) {
                int i = tid * 4 + j;
                if (i < CB) countmat[(size_t)i * nbkt + b] = run;
                run += v[j];
            }
            if (tid == BLK - 1) total[b] = s[BLK - 1];
            __syncthreads();
        }
    }
    grid.sync();

    // ---- Phase C: packed scatter into bucket-major order ----
    {
        int* s    = (int*)smem;
        int* base = s + 256;
        int* h    = base + 256;
        for (int bb = blockIdx.x; bb < CB; bb += gridDim.x) {
            int tv = (tid < nbkt) ? total[tid] : 0;
            s[tid] = tv;
            __syncthreads();
            #pragma unroll
            for (int off = 1; off < BLK; off <<= 1) {
                int t = 0;
                if (tid >= off) t = s[tid - off];
                __syncthreads();
                if (tid >= off) s[tid] += t;
                __syncthreads();
            }
            base[tid] = s[tid] - tv;
            h[tid] = 0;
            __syncthreads();
            if (bb == 0) {
                if (tid < nbkt) bbase[tid] = base[tid];
                if (tid == 0) bbase[nbkt] = E;
            }
            int e0 = bb * 1024;
            int lim = min(e0 + 1024, E);
            const int* myoff = countmat + (size_t)bb * nbkt;
            for (int e = e0 + tid; e < lim; e += 256) {
                int d = dst[e];
                unsigned w = ((unsigned)(d & 255) << 24) | (unsigned)srcp[e];
                int b = d >> 8;
                int lr = atomicAdd(&h[b], 1);            // LDS
                sorted[base[b] + myoff[b] + lr] = w;
            }
            __syncthreads();
        }
    }
    grid.sync();

    // ---- Phase D: per-bucket CSR finalize + layer-1 MFMA GEMM (fp8 hs) ----
    {
        int*   h   = (int*)smem;
        int*   s   = h + 256;
        int*   cur = s + 256;
        float* dvl = (float*)(cur + 256);
        const int wave  = tid >> 6;
        const int lane  = tid & 63;
        const int l15   = lane & 15;
        const int khalf = lane >> 4;
        for (int b = blockIdx.x; b < nbkt; b += gridDim.x) {
            int eb0 = bbase[b], eb1 = bbase[b + 1];
            h[tid] = 0;
            __syncthreads();
            for (int e = eb0 + tid; e < eb1; e += 256) atomicAdd(&h[sorted[e] >> 24], 1);
            __syncthreads();
            int hv = h[tid];
            s[tid] = hv;
            __syncthreads();
            #pragma unroll
            for (int off = 1; off < BLK; off <<= 1) {
                int t = 0;
                if (tid >= off) t = s[tid - off];
                __syncthreads();
                if (tid >= off) s[tid] += t;
                __syncthreads();
            }
            int sc = s[tid] - hv;
            int node = b * 256 + tid;
            float dv = rsqrtf((float)(hv + 1));
            dvl[tid] = dv;
            if (node < N) {
                rowptr[node] = eb0 + sc;
                dinv[node] = dv;
            }
            cur[tid] = sc;
            if (b == 0 && tid == 0) rowptr[N] = E;
            __syncthreads();
            for (int e = eb0 + tid; e < eb1; e += 256) {
                unsigned w = sorted[e];
                int lr = atomicAdd(&cur[w >> 24], 1);    // LDS
                csr_src[eb0 + lr] = (int)(w & 0xFFFFFFu);
            }
            __syncthreads();

            for (int sub = 0; sub < 4; ++sub) {
                const int rowA = b * 256 + sub * 64 + wave * 16 + l15;
                half8 a[4];
                #pragma unroll
                for (int ks = 0; ks < 4; ++ks) {
                    if (rowA < N) {
                        const float* px = &x[(size_t)rowA * 128 + ks * 32 + khalf * 8];
                        float4 f0 = *(const float4*)&px[0];
                        float4 f1 = *(const float4*)&px[4];
                        union { half8 h8; __half2 h2[4]; } u;
                        u.h2[0] = __floats2half2_rn(f0.x, f0.y);
                        u.h2[1] = __floats2half2_rn(f0.z, f0.w);
                        u.h2[2] = __floats2half2_rn(f1.x, f1.y);
                        u.h2[3] = __floats2half2_rn(f1.z, f1.w);
                        a[ks] = u.h8;
                    } else {
                        half8 z = {0, 0, 0, 0, 0, 0, 0, 0};
                        a[ks] = z;
                    }
                }
                const int lrow0 = sub * 64 + wave * 16 + khalf * 4;
                #pragma unroll
                for (int ct = 0; ct < 8; ++ct) {
                    f32x4 acc = {0.f, 0.f, 0.f, 0.f};
                    #pragma unroll
                    for (int ks = 0; ks < 4; ++ks) {
                        half8 bb8 = *(const half8*)&wt0[(size_t)(ct * 16 + l15) * 128 + ks * 32 + khalf * 8];
                        acc = __builtin_amdgcn_mfma_f32_16x16x32_f16(a[ks], bb8, acc, 0, 0, 0);
                    }
                    const int col = ct * 16 + l15;
                    #pragma unroll
                    for (int i = 0; i < 4; ++i) {
                        int r = b * 256 + lrow0 + i;
                        if (r < N) {
                            float f = acc[i] * dvl[lrow0 + i];
                            unsigned int b8 = (unsigned int)__builtin_amdgcn_cvt_pk_fp8_f32(f, f, 0, 0);
                            hs8[(size_t)r * 128 + col] = (unsigned char)(b8 & 0xff);
                        }
                    }
                }
            }
            __syncthreads();
        }
    }
    grid.sync();

    // ---- Phase E: layer-1 aggregate (fp8 gather + sigmoid) + fused layer-2 GEMM ----
    {
        _Float16 (*act_lds)[136] = (_Float16(*)[136])smem;
        float* dvl = (float*)(smem + 16 * 136 * 2);
        const int nl = tid >> 4;
        const int p  = tid & 15;
        const int wave  = tid >> 6;
        const int lane  = tid & 63;
        const int l15   = lane & 15;
        const int khalf = lane >> 4;
        const int EB = (N + 15) / 16;
        for (int bb = blockIdx.x; bb < EB; bb += gridDim.x) {
            const int node = bb * 16 + nl;
            const bool valid = node < N;
            float acc[8];
            #pragma unroll
            for (int j = 0; j < 8; ++j) acc[j] = 0.0f;
            if (valid) {
                const unsigned char* __restrict__ hp = hs8 + p * 8;
                fp8x8_add(*(const uint2*)&hp[(size_t)node * 128], acc);
                int e        = rowptr[node];
                const int e1 = rowptr[node + 1];
                for (; e + 8 <= e1; e += 8) {
                    int s[8];
                    #pragma unroll
                    for (int u = 0; u < 8; ++u) s[u] = csr_src[e + u];
                    uint2 r[8];
                    #pragma unroll
                    for (int u = 0; u < 8; ++u) r[u] = *(const uint2*)&hp[(size_t)s[u] * 128];
                    #pragma unroll
                    for (int u = 0; u < 8; ++u) fp8x8_add(r[u], acc);
                }
                for (; e + 4 <= e1; e += 4) {
                    int s[4];
                    #pragma unroll
                    for (int u = 0; u < 4; ++u) s[u] = csr_src[e + u];
                    uint2 r[4];
                    #pragma unroll
                    for (int u = 0; u < 4; ++u) r[u] = *(const uint2*)&hp[(size_t)s[u] * 128];
                    #pragma unroll
                    for (int u = 0; u < 4; ++u) fp8x8_add(r[u], acc);
                }
                for (; e < e1; ++e) fp8x8_add(*(const uint2*)&hp[(size_t)csr_src[e] * 128], acc);
                const float sc = dinv[node];
                #pragma unroll
                for (int j = 0; j < 8; ++j) {
                    float v = acc[j] * sc + b0[p * 8 + j];
                    acc[j] = 1.0f / (1.0f + expf(-v));
                }
            }
            #pragma unroll
            for (int j = 0; j < 8; ++j) act_lds[nl][p * 8 + j] = (_Float16)acc[j];
            if (p == 0) dvl[nl] = valid ? dinv[node] : 0.0f;
            __syncthreads();

            half8 a[4];
            #pragma unroll
            for (int ks = 0; ks < 4; ++ks)
                a[ks] = *(const half8*)&act_lds[l15][ks * 32 + khalf * 8];
            f32x4 acc2 = {0.f, 0.f, 0.f, 0.f};
            #pragma unroll
            for (int ks = 0; ks < 4; ++ks) {
                half8 bb8 = *(const half8*)&wt1[(size_t)(wave * 16 + l15) * 128 + ks * 32 + khalf * 8];
                acc2 = __builtin_amdgcn_mfma_f32_16x16x32_f16(a[ks], bb8, acc2, 0, 0, 0);
            }
            const int col = wave * 16 + l15;
            _Float16* __restrict__ hs2f = (_Float16*)hs2;
            #pragma unroll
            for (int i = 0; i < 4; ++i) {
                int lr = khalf * 4 + i;
                int r  = bb * 16 + lr;
                if (r < N) hs2f[(size_t)r * 64 + col] = (_Float16)(acc2[i] * dvl[lr]);
            }
            __syncthreads();
        }
    }
    grid.sync();

    // ---- Phase F: layer-2 aggregate (fp16 gather) -> fp32 out ----
    {
        const int FB = (N + 31) / 32;
        const int p  = tid & 7;
        for (int bb = blockIdx.x; bb < FB; bb += gridDim.x) {
            const int node = bb * 32 + (tid >> 3);
            if (node >= N) continue;
            const __half* __restrict__ hp = hs2 + (size_t)p * 8;
            float acc[8];
            {
                float4 raw = *(const float4*)&hp[(size_t)node * 64];
                const __half2* h2 = (const __half2*)&raw;
                #pragma unroll
                for (int j = 0; j < 4; ++j) {
                    float2 f = __half22float2(h2[j]);
                    acc[2 * j] = f.x; acc[2 * j + 1] = f.y;
                }
            }
            int e        = rowptr[node];
            const int e1 = rowptr[node + 1];
            for (; e + 8 <= e1; e += 8) {
                int s[8];
                #pragma unroll
                for (int u = 0; u < 8; ++u) s[u] = csr_src[e + u];
                float4 r[8];
                #pragma unroll
                for (int u = 0; u < 8; ++u) r[u] = *(const float4*)&hp[(size_t)s[u] * 64];
                #pragma unroll
                for (int j = 0; j < 4; ++j) {
                    #pragma unroll
                    for (int u = 0; u < 8; ++u) {
                        float2 f = __half22float2(((const __half2*)&r[u])[j]);
                        acc[2 * j] += f.x; acc[2 * j + 1] += f.y;
                    }
                }
            }
            for (; e + 4 <= e1; e += 4) {
                int s[4];
                #pragma unroll
                for (int u = 0; u < 4; ++u) s[u] = csr_src[e + u];
                float4 r[4];
                #pragma unroll
                for (int u = 0; u < 4; ++u) r[u] = *(const float4*)&hp[(size_t)s[u] * 64];
                #pragma unroll
                for (int j = 0; j < 4; ++j) {
                    #pragma unroll
                    for (int u = 0; u < 4; ++u) {
                        float2 f = __half22float2(((const __half2*)&r[u])[j]);
                        acc[2 * j] += f.x; acc[2 * j + 1] += f.y;
                    }
                }
            }
            for (; e < e1; ++e) {
                float4 r = *(const float4*)&hp[(size_t)csr_src[e] * 64];
                const __half2* a2 = (const __half2*)&r;
                #pragma unroll
                for (int j = 0; j < 4; ++j) {
                    float2 f = __half22float2(a2[j]);
                    acc[2 * j] += f.x; acc[2 * j + 1] += f.y;
                }
            }
            const float sc = dinv[node];
            float* o = &out[(size_t)node * 64 + p * 8];
            #pragma unroll
            for (int j = 0; j < 8; ++j) acc[j] = acc[j] * sc + b1[p * 8 + j];
            *(float4*)&o[0] = make_float4(acc[0], acc[1], acc[2], acc[3]);
            *(float4*)&o[4] = make_float4(acc[4], acc[5], acc[6], acc[7]);
        }
    }
}

static inline size_t align256(size_t x) { return (x + 255) & ~size_t(255); }

extern "C" void kernel_launch(void* const* d_in, const int* in_sizes, int n_in,
                              void* d_out, int out_size, void* d_ws, size_t ws_size,
                              hipStream_t stream) {
    const float* x   = (const float*)d_in[0];
    const int*   e32 = (const int*)d_in[1];   // [2,E] int32
    const float* W0  = (const float*)d_in[2];
    const float* b0  = (const float*)d_in[3];
    const float* W1  = (const float*)d_in[4];
    const float* b1  = (const float*)d_in[5];
    float* out = (float*)d_out;

    const int N = in_sizes[0] / 128;   // 50000
    const int E = in_sizes[1] / 2;     // 800000
    const int* src = e32;
    const int* dst = e32 + E;

    const int nbkt = (N + 255) >> 8;          // 196
    const int CB   = (E + 1023) >> 10;        // 782

    // Workspace layout
    char* p = (char*)d_ws;
    int*           countmat = (int*)p;           p += align256((size_t)CB * nbkt * 4);
    int*           total    = (int*)p;           p += align256((size_t)256 * 4);
    int*           bbase    = (int*)p;           p += align256((size_t)(nbkt + 1) * 4);
    unsigned*      sorted   = (unsigned*)p;      p += align256((size_t)E * 4);
    int*           rowptr   = (int*)p;           p += align256((size_t)(N + 1) * 4);
    float*         dinv     = (float*)p;         p += align256((size_t)N * 4);
    int*           csr_src  = (int*)p;           p += align256((size_t)E * 4);
    unsigned char* hs8      = (unsigned char*)p; p += align256((size_t)N * 128);
    __half*        hs2      = (__half*)p;        p += align256((size_t)N * 64 * 2);
    __half*        wt0      = (__half*)p;        p += align256((size_t)128 * 128 * 2);
    __half*        wt1      = (__half*)p;        p += align256((size_t)64 * 128 * 2);

    int occ = 0;
    (void)hipOccupancyMaxActiveBlocksPerMultiprocessor(&occ, mega_kernel, BLK, 0);
    if (occ < 1) occ = 1;
    int grid = occ * 256;                  // 256 CUs on MI355X
    if (grid > 1024) grid = 1024;

    void* args[] = {
        (void*)&dst, (void*)&src, (void*)&countmat, (void*)&total, (void*)&bbase,
        (void*)&sorted, (void*)&rowptr, (void*)&dinv, (void*)&csr_src,
        (void*)&hs8, (void*)&hs2, (void*)&wt0, (void*)&wt1,
        (void*)&W0, (void*)&W1, (void*)&x, (void*)&b0, (void*)&b1, (void*)&out,
        (void*)&N, (void*)&E, (void*)&nbkt, (void*)&CB
    };
    hipLaunchCooperativeKernel((const void*)mega_kernel, dim3(grid), dim3(BLK),
                               args, 0, stream);
}

// Round 19
// 97.036 us; speedup vs baseline: 4.7399x; 4.7399x over previous
//
#include <hip/hip_runtime.h>
#include <hip/hip_fp16.h>
#include <math.h>

#define BLK 256

typedef _Float16 half8 __attribute__((ext_vector_type(8)));
typedef float f32x4 __attribute__((ext_vector_type(4)));
typedef float f32x2 __attribute__((ext_vector_type(2)));

// ---------------- K1: per-chunk bucket histogram + weight convert (block-split) ----------------
__global__ void count_init_kernel(const int* __restrict__ dst, int* __restrict__ countmat,
                                  int E, int nbkt, int CB,
                                  const float* __restrict__ W0, const float* __restrict__ W1,
                                  __half* __restrict__ wt0, __half* __restrict__ wt1) {
    __shared__ int h[256];
    int bid = blockIdx.x, tid = threadIdx.x;
    if (bid < CB) {
        h[tid] = 0;
        __syncthreads();
        int e0 = bid * 1024;
        int lim = min(e0 + 1024, E);
        for (int e = e0 + tid; e < lim; e += 256) atomicAdd(&h[dst[e] >> 8], 1);
        __syncthreads();
        if (tid < nbkt) countmat[(size_t)bid * nbkt + tid] = h[tid];
    } else {
        int u = (bid - CB) * 256 + tid;
        if (u < 128 * 128) {
            int c = u >> 7, k = u & 127;
            wt0[u] = __float2half(W0[k * 128 + c]);
        } else if (u < 128 * 128 + 64 * 128) {
            int v = u - 128 * 128;
            int c = v >> 7, k = v & 127;
            wt1[v] = __float2half(W1[k * 64 + c]);
        }
    }
}

// ---------------- K2: per-bucket exclusive scan over chunk-blocks (grid = nbkt) ----------------
__global__ void colscan_kernel(int* __restrict__ countmat, int* __restrict__ total,
                               int CB, int nbkt) {
    __shared__ int s[BLK];
    int b = blockIdx.x, tid = threadIdx.x;
    int v[4];
    int sum = 0;
    #pragma unroll
    for (int j = 0; j < 4; ++j) {
        int i = tid * 4 + j;
        v[j] = (i < CB) ? countmat[(size_t)i * nbkt + b] : 0;
        sum += v[j];
    }
    s[tid] = sum;
    __syncthreads();
    #pragma unroll
    for (int off = 1; off < BLK; off <<= 1) {
        int t = 0;
        if (tid >= off) t = s[tid - off];
        __syncthreads();
        if (tid >= off) s[tid] += t;
        __syncthreads();
    }
    int run = s[tid] - sum;
    #pragma unroll
    for (int j = 0; j < 4; ++j) {
        int i = tid * 4 + j;
        if (i < CB) countmat[(size_t)i * nbkt + b] = run;
        run += v[j];
    }
    if (tid == BLK - 1) total[b] = s[BLK - 1];
}

// ---------------- K3: scatter edges into bucket-major order, PACKED uint32 ----------------
// word = (dst&255)<<24 | src  (src < 2^24). LDS atomics only.
__global__ void scatter_kernel(const int* __restrict__ dst, const int* __restrict__ src,
                               const int* __restrict__ countmat, const int* __restrict__ total,
                               unsigned* __restrict__ sorted, int* __restrict__ bbase,
                               int E, int nbkt) {
    __shared__ int s[BLK];
    __shared__ int base[256];
    __shared__ int h[256];
    int tid = threadIdx.x;
    int tv = (tid < nbkt) ? total[tid] : 0;
    s[tid] = tv;
    __syncthreads();
    #pragma unroll
    for (int off = 1; off < BLK; off <<= 1) {
        int t = 0;
        if (tid >= off) t = s[tid - off];
        __syncthreads();
        if (tid >= off) s[tid] += t;
        __syncthreads();
    }
    base[tid] = s[tid] - tv;
    h[tid] = 0;
    __syncthreads();
    if (blockIdx.x == 0) {
        if (tid < nbkt) bbase[tid] = base[tid];
        if (tid == 0) bbase[nbkt] = E;
    }
    int e0 = blockIdx.x * 1024;
    int lim = min(e0 + 1024, E);
    const int* myoff = countmat + (size_t)blockIdx.x * nbkt;
    for (int e = e0 + tid; e < lim; e += 256) {
        int d = dst[e];
        unsigned w = ((unsigned)(d & 255) << 24) | (unsigned)src[e];
        int b = d >> 8;
        int lr = atomicAdd(&h[b], 1);            // LDS
        sorted[base[b] + myoff[b] + lr] = w;
    }
}

// ---------------- K4: per-bucket CSR finalize + layer-1 MFMA GEMM for the bucket's rows ----------------
__global__ __launch_bounds__(256) void csr_gemm1_kernel(
    const unsigned* __restrict__ sorted, const int* __restrict__ bbase,
    int* __restrict__ rowptr, float* __restrict__ dinv, int* __restrict__ csr_src,
    int N, int E,
    const float* __restrict__ x, const __half* __restrict__ wt0,
    unsigned char* __restrict__ hs8) {
    __shared__ int h[256];
    __shared__ int s[BLK];
    __shared__ int cur[256];
    __shared__ float dinv_lds[256];
    int b = blockIdx.x, tid = threadIdx.x;
    int eb0 = bbase[b], eb1 = bbase[b + 1];
    h[tid] = 0;
    __syncthreads();
    for (int e = eb0 + tid; e < eb1; e += 256) atomicAdd(&h[sorted[e] >> 24], 1);
    __syncthreads();
    int hv = h[tid];
    s[tid] = hv;
    __syncthreads();
    #pragma unroll
    for (int off = 1; off < BLK; off <<= 1) {
        int t = 0;
        if (tid >= off) t = s[tid - off];
        __syncthreads();
        if (tid >= off) s[tid] += t;
        __syncthreads();
    }
    int sc = s[tid] - hv;   // exclusive within bucket
    int node = b * 256 + tid;
    float dv = rsqrtf((float)(hv + 1));
    dinv_lds[tid] = dv;
    if (node < N) {
        rowptr[node] = eb0 + sc;
        dinv[node] = dv;
    }
    cur[tid] = sc;
    if (b == 0 && tid == 0) rowptr[N] = E;
    __syncthreads();
    for (int e = eb0 + tid; e < eb1; e += 256) {
        unsigned w = sorted[e];
        int lr = atomicAdd(&cur[w >> 24], 1);    // LDS
        csr_src[eb0 + lr] = (int)(w & 0xFFFFFFu);
    }
    __syncthreads();

    // ---- gemm1 for rows [b*256, b*256+256): hs8 = fp8((x @ W0) * dinv) ----
    const int wave  = tid >> 6;
    const int lane  = tid & 63;
    const int l15   = lane & 15;
    const int khalf = lane >> 4;

    for (int sub = 0; sub < 4; ++sub) {
        const int rowA = b * 256 + sub * 64 + wave * 16 + l15;
        half8 a[4];
        #pragma unroll
        for (int ks = 0; ks < 4; ++ks) {
            if (rowA < N) {
                const float* px = &x[(size_t)rowA * 128 + ks * 32 + khalf * 8];
                float4 f0 = *(const float4*)&px[0];
                float4 f1 = *(const float4*)&px[4];
                union { half8 h8; __half2 h2[4]; } u;
                u.h2[0] = __floats2half2_rn(f0.x, f0.y);
                u.h2[1] = __floats2half2_rn(f0.z, f0.w);
                u.h2[2] = __floats2half2_rn(f1.x, f1.y);
                u.h2[3] = __floats2half2_rn(f1.z, f1.w);
                a[ks] = u.h8;
            } else {
                half8 z = {0, 0, 0, 0, 0, 0, 0, 0};
                a[ks] = z;
            }
        }
        const int lrow0 = sub * 64 + wave * 16 + khalf * 4;
        #pragma unroll
        for (int ct = 0; ct < 8; ++ct) {
            f32x4 acc = {0.f, 0.f, 0.f, 0.f};
            #pragma unroll
            for (int ks = 0; ks < 4; ++ks) {
                half8 bb = *(const half8*)&wt0[(size_t)(ct * 16 + l15) * 128 + ks * 32 + khalf * 8];
                acc = __builtin_amdgcn_mfma_f32_16x16x32_f16(a[ks], bb, acc, 0, 0, 0);
            }
            const int col = ct * 16 + l15;
            #pragma unroll
            for (int i = 0; i < 4; ++i) {
                int r = b * 256 + lrow0 + i;
                if (r < N) {
                    float f = acc[i] * dinv_lds[lrow0 + i];
                    unsigned int b8 = (unsigned int)__builtin_amdgcn_cvt_pk_fp8_f32(f, f, 0, 0);
                    hs8[(size_t)r * 128 + col] = (unsigned char)(b8 & 0xff);
                }
            }
        }
    }
}

// ---------------- fp8 decode helper (packed, word-sel literal) ----------------
__device__ inline void fp8x8_add(uint2 r, float* __restrict__ acc) {
    f32x2 f01 = __builtin_amdgcn_cvt_pk_f32_fp8((int)r.x, false);
    f32x2 f23 = __builtin_amdgcn_cvt_pk_f32_fp8((int)r.x, true);
    f32x2 f45 = __builtin_amdgcn_cvt_pk_f32_fp8((int)r.y, false);
    f32x2 f67 = __builtin_amdgcn_cvt_pk_f32_fp8((int)r.y, true);
    acc[0] += f01[0]; acc[1] += f01[1];
    acc[2] += f23[0]; acc[3] += f23[1];
    acc[4] += f45[0]; acc[5] += f45[1];
    acc[6] += f67[0]; acc[7] += f67[1];
}

// ---------------- K5: layer-1 aggregate (fp8 gather, sigmoid) + fused layer-2 GEMM ----------------
__global__ __launch_bounds__(256) void agg8_gemm2_kernel(
    const int* __restrict__ rowptr, const int* __restrict__ csr_src,
    const unsigned char* __restrict__ hs8, const float* __restrict__ dinv,
    const float* __restrict__ bias, const __half* __restrict__ wt1,
    __half* __restrict__ hs2, int n) {
    __shared__ _Float16 act_lds[16][136];   // 272B row: 16B-aligned, 2-way-bank free
    __shared__ float dinv_lds[16];
    const int tid  = threadIdx.x;
    const int nl   = tid >> 4;
    const int p    = tid & 15;
    const int node = blockIdx.x * 16 + nl;
    const bool valid = node < n;

    float acc[8];
    #pragma unroll
    for (int j = 0; j < 8; ++j) acc[j] = 0.0f;

    if (valid) {
        const unsigned char* __restrict__ hp = hs8 + p * 8;
        fp8x8_add(*(const uint2*)&hp[(size_t)node * 128], acc);   // self-loop

        int e        = rowptr[node];
        const int e1 = rowptr[node + 1];
        for (; e + 8 <= e1; e += 8) {
            int s[8];
            #pragma unroll
            for (int u = 0; u < 8; ++u) s[u] = csr_src[e + u];
            uint2 r[8];
            #pragma unroll
            for (int u = 0; u < 8; ++u) r[u] = *(const uint2*)&hp[(size_t)s[u] * 128];
            #pragma unroll
            for (int u = 0; u < 8; ++u) fp8x8_add(r[u], acc);
        }
        for (; e + 4 <= e1; e += 4) {
            int s[4];
            #pragma unroll
            for (int u = 0; u < 4; ++u) s[u] = csr_src[e + u];
            uint2 r[4];
            #pragma unroll
            for (int u = 0; u < 4; ++u) r[u] = *(const uint2*)&hp[(size_t)s[u] * 128];
            #pragma unroll
            for (int u = 0; u < 4; ++u) fp8x8_add(r[u], acc);
        }
        for (; e < e1; ++e) {
            int s = csr_src[e];
            fp8x8_add(*(const uint2*)&hp[(size_t)s * 128], acc);
        }

        const float sc = dinv[node];
        #pragma unroll
        for (int j = 0; j < 8; ++j) {
            float v = acc[j] * sc + bias[p * 8 + j];
            acc[j] = 1.0f / (1.0f + expf(-v));   // sigmoid
        }
    }
    #pragma unroll
    for (int j = 0; j < 8; ++j) act_lds[nl][p * 8 + j] = (_Float16)acc[j];
    if (p == 0) dinv_lds[nl] = valid ? dinv[node] : 0.0f;
    __syncthreads();

    // ---- phase 2: hs2[rows 16] = fp16((act @ W1) * dinv) ----
    const int wave  = tid >> 6;            // = output col tile ct
    const int lane  = tid & 63;
    const int l15   = lane & 15;
    const int khalf = lane >> 4;

    half8 a[4];
    #pragma unroll
    for (int ks = 0; ks < 4; ++ks)
        a[ks] = *(const half8*)&act_lds[l15][ks * 32 + khalf * 8];

    f32x4 acc2 = {0.f, 0.f, 0.f, 0.f};
    #pragma unroll
    for (int ks = 0; ks < 4; ++ks) {
        half8 bb = *(const half8*)&wt1[(size_t)(wave * 16 + l15) * 128 + ks * 32 + khalf * 8];
        acc2 = __builtin_amdgcn_mfma_f32_16x16x32_f16(a[ks], bb, acc2, 0, 0, 0);
    }
    const int col = wave * 16 + l15;
    _Float16* __restrict__ hs2f = (_Float16*)hs2;
    #pragma unroll
    for (int i = 0; i < 4; ++i) {
        int lr = khalf * 4 + i;
        int r  = blockIdx.x * 16 + lr;
        if (r < n) hs2f[(size_t)r * 64 + col] = (_Float16)(acc2[i] * dinv_lds[lr]);
    }
}

// ---------------- K6: layer-2 aggregate (fp16 hs2, fp32 out) ----------------
__global__ void aggregate64_kernel(const int* __restrict__ rowptr, const int* __restrict__ csr_src,
                                   const __half* __restrict__ hs, const float* __restrict__ dinv,
                                   const float* __restrict__ bias, float* __restrict__ out, int n) {
    const int tid  = threadIdx.x;
    const int node = blockIdx.x * 32 + (tid >> 3);
    const int p    = tid & 7;
    if (node >= n) return;

    const __half* __restrict__ hp = hs + (size_t)p * 8;

    float acc[8];
    {
        float4 raw = *(const float4*)&hp[(size_t)node * 64];
        const __half2* h2 = (const __half2*)&raw;
        #pragma unroll
        for (int j = 0; j < 4; ++j) {
            float2 f = __half22float2(h2[j]);
            acc[2 * j] = f.x; acc[2 * j + 1] = f.y;
        }
    }

    int e        = rowptr[node];
    const int e1 = rowptr[node + 1];

    for (; e + 8 <= e1; e += 8) {
        int s[8];
        #pragma unroll
        for (int u = 0; u < 8; ++u) s[u] = csr_src[e + u];
        float4 r[8];
        #pragma unroll
        for (int u = 0; u < 8; ++u) r[u] = *(const float4*)&hp[(size_t)s[u] * 64];
        #pragma unroll
        for (int j = 0; j < 4; ++j) {
            #pragma unroll
            for (int u = 0; u < 8; ++u) {
                float2 f = __half22float2(((const __half2*)&r[u])[j]);
                acc[2 * j] += f.x; acc[2 * j + 1] += f.y;
            }
        }
    }
    for (; e + 4 <= e1; e += 4) {
        int s[4];
        #pragma unroll
        for (int u = 0; u < 4; ++u) s[u] = csr_src[e + u];
        float4 r[4];
        #pragma unroll
        for (int u = 0; u < 4; ++u) r[u] = *(const float4*)&hp[(size_t)s[u] * 64];
        #pragma unroll
        for (int j = 0; j < 4; ++j) {
            #pragma unroll
            for (int u = 0; u < 4; ++u) {
                float2 f = __half22float2(((const __half2*)&r[u])[j]);
                acc[2 * j] += f.x; acc[2 * j + 1] += f.y;
            }
        }
    }
    for (; e < e1; ++e) {
        int s = csr_src[e];
        float4 r = *(const float4*)&hp[(size_t)s * 64];
        const __half2* a = (const __half2*)&r;
        #pragma unroll
        for (int j = 0; j < 4; ++j) {
            float2 f = __half22float2(a[j]);
            acc[2 * j] += f.x; acc[2 * j + 1] += f.y;
        }
    }

    const float sc = dinv[node];
    float* o = &out[(size_t)node * 64 + p * 8];
    #pragma unroll
    for (int j = 0; j < 8; ++j) acc[j] = acc[j] * sc + bias[p * 8 + j];
    *(float4*)&o[0] = make_float4(acc[0], acc[1], acc[2], acc[3]);
    *(float4*)&o[4] = make_float4(acc[4], acc[5], acc[6], acc[7]);
}

static inline size_t align256(size_t x) { return (x + 255) & ~size_t(255); }

extern "C" void kernel_launch(void* const* d_in, const int* in_sizes, int n_in,
                              void* d_out, int out_size, void* d_ws, size_t ws_size,
                              hipStream_t stream) {
    const float* x   = (const float*)d_in[0];
    const int*   e32 = (const int*)d_in[1];   // [2,E] int32
    const float* W0  = (const float*)d_in[2];
    const float* b0  = (const float*)d_in[3];
    const float* W1  = (const float*)d_in[4];
    const float* b1  = (const float*)d_in[5];
    float* out = (float*)d_out;

    const int N = in_sizes[0] / 128;   // 50000
    const int E = in_sizes[1] / 2;     // 800000
    const int* src = e32;
    const int* dst = e32 + E;

    const int nbkt = (N + 255) >> 8;          // 196 (requires N <= 65536 and src < 2^24)
    const int CB   = (E + 1023) >> 10;        // 782 chunk-blocks (<= 1024)
    const int WG   = (128 * 128 + 64 * 128 + BLK - 1) / BLK;  // 96 weight-convert blocks

    // Workspace layout
    char* p = (char*)d_ws;
    int*           countmat = (int*)p;           p += align256((size_t)CB * nbkt * 4);
    int*           total    = (int*)p;           p += align256((size_t)256 * 4);
    int*           bbase    = (int*)p;           p += align256((size_t)(nbkt + 1) * 4);
    unsigned*      sorted   = (unsigned*)p;      p += align256((size_t)E * 4);
    int*           rowptr   = (int*)p;           p += align256((size_t)(N + 1) * 4);
    float*         dinv     = (float*)p;         p += align256((size_t)N * 4);
    int*           csr_src  = (int*)p;           p += align256((size_t)E * 4);
    unsigned char* hs8      = (unsigned char*)p; p += align256((size_t)N * 128);      // fp8 layer-1 hs
    __half*        hs2      = (__half*)p;        p += align256((size_t)N * 64 * 2);   // fp16 layer-2 hs
    __half*        wt0      = (__half*)p;        p += align256((size_t)128 * 128 * 2);
    __half*        wt1      = (__half*)p;        p += align256((size_t)64 * 128 * 2);

    // ---- K1: chunk histograms + weight convert ----
    count_init_kernel<<<CB + WG, BLK, 0, stream>>>(dst, countmat, E, nbkt, CB, W0, W1, wt0, wt1);
    // ---- K2: per-bucket scan ----
    colscan_kernel<<<nbkt, BLK, 0, stream>>>(countmat, total, CB, nbkt);
    // ---- K3: packed scatter ----
    scatter_kernel<<<CB, BLK, 0, stream>>>(dst, src, countmat, total, sorted, bbase, E, nbkt);
    // ---- K4: CSR finalize + layer-1 GEMM ----
    csr_gemm1_kernel<<<nbkt, BLK, 0, stream>>>(sorted, bbase, rowptr, dinv, csr_src, N, E,
                                               x, wt0, hs8);
    // ---- K5: layer-1 aggregate + layer-2 GEMM ----
    agg8_gemm2_kernel<<<(N + 15) / 16, BLK, 0, stream>>>(rowptr, csr_src, hs8, dinv, b0, wt1,
                                                         hs2, N);
    // ---- K6: layer-2 aggregate ----
    aggregate64_kernel<<<(N + 31) / 32, BLK, 0, stream>>>(rowptr, csr_src, hs2, dinv, b1, out, N);
}